// Round 1
// baseline (1784.715 us; speedup 1.0000x reference)
//
#include <hip/hip_runtime.h>

#define NROWS 6144
#define DIN1 3000
#define DIN2 512

__device__ __forceinline__ float spikef(float y) {
    float t = 4.0f * y;
    t = fminf(fmaxf(t, 0.0f), 4.0f);
    return floorf(t + 0.5f) * 0.25f;
}

__device__ __forceinline__ void fma_outer(float (&acc)[4][4], const float4& a, const float4& b) {
    const float av[4] = {a.x, a.y, a.z, a.w};
    const float bv[4] = {b.x, b.y, b.z, b.w};
#pragma unroll
    for (int i = 0; i < 4; i++)
#pragma unroll
        for (int j = 0; j < 4; j++)
            acc[i][j] += av[i] * bv[j];
}

__device__ __forceinline__ void fma_row(float (&acc)[4], const float4& a,
                                        const float4& b0, const float4& b1,
                                        const float4& b2, const float4& b3) {
    acc[0] += a.x * b0.x + a.y * b1.x + a.z * b2.x + a.w * b3.x;
    acc[1] += a.x * b0.y + a.y * b1.y + a.z * b2.y + a.w * b3.y;
    acc[2] += a.x * b0.z + a.y * b1.z + a.z * b2.z + a.w * b3.z;
    acc[3] += a.x * b0.w + a.y * b1.w + a.z * b2.w + a.w * b3.w;
}

// C_partial = A1 @ B (and optionally + A2 @ B, combined with conv weights cw).
// A: NROWS x K row-major (lda), B: K x 64 row-major.
// grid.x = NROWS/64 row blocks, grid.y = S split-k slices, grid.z selects A1/A1alt + P bank.
// P[z][s][row][col].
template <bool DUAL>
__global__ __launch_bounds__(256) void gemm_dual(
    const float* __restrict__ A1, const float* __restrict__ A1alt,
    const float* __restrict__ A2, const float* __restrict__ B,
    const float* __restrict__ cw, float* __restrict__ P,
    int K, int lda, int kchunk, size_t bank_stride)
{
    __shared__ __align__(16) float As1[64][36];
    __shared__ __align__(16) float As2[64][36];
    __shared__ __align__(16) float Bs[32][64];

    const float* A = blockIdx.z ? A1alt : A1;
    float* Pz = P + (size_t)blockIdx.z * bank_stride;

    int tid = threadIdx.x;
    int r0 = blockIdx.x * 64;
    int s = blockIdx.y;
    int k0 = s * kchunk;
    int kend = min(K, k0 + kchunk);
    int ty = tid >> 4, tx = tid & 15;

    float acc1[4][4] = {};
    float acc2[4][4] = {};

    for (int kb = k0; kb < kend; kb += 32) {
        __syncthreads();
        // stage A tiles: 64 rows x 32 k
#pragma unroll
        for (int i = 0; i < 2; i++) {
            int q = tid + i * 256;
            int row = q >> 3;
            int kq = (q & 7) * 4;
            int k = kb + kq;
            float4 z = make_float4(0.f, 0.f, 0.f, 0.f);
            if (k + 4 <= kend) {
                z = *(const float4*)(A + (size_t)(r0 + row) * lda + k);
            } else {
                float* zp = (float*)&z;
                for (int j = 0; j < 4; j++)
                    if (k + j < kend) zp[j] = A[(size_t)(r0 + row) * lda + k + j];
            }
            *(float4*)(&As1[row][kq]) = z;
            if (DUAL) {
                float4 z2 = make_float4(0.f, 0.f, 0.f, 0.f);
                if (k + 4 <= kend) {
                    z2 = *(const float4*)(A2 + (size_t)(r0 + row) * lda + k);
                } else {
                    float* zp = (float*)&z2;
                    for (int j = 0; j < 4; j++)
                        if (k + j < kend) zp[j] = A2[(size_t)(r0 + row) * lda + k + j];
                }
                *(float4*)(&As2[row][kq]) = z2;
            }
        }
        // stage B tile: 32 k x 64 cols
#pragma unroll
        for (int i = 0; i < 2; i++) {
            int q = tid + i * 256;
            int kk = q >> 4;
            int cq = (q & 15) * 4;
            int k = kb + kk;
            float4 z = make_float4(0.f, 0.f, 0.f, 0.f);
            if (k < kend) z = *(const float4*)(B + (size_t)k * 64 + cq);
            *(float4*)(&Bs[kk][cq]) = z;
        }
        __syncthreads();

#pragma unroll
        for (int ku = 0; ku < 32; ku += 4) {
            float4 b0 = *(const float4*)(&Bs[ku + 0][tx * 4]);
            float4 b1 = *(const float4*)(&Bs[ku + 1][tx * 4]);
            float4 b2 = *(const float4*)(&Bs[ku + 2][tx * 4]);
            float4 b3 = *(const float4*)(&Bs[ku + 3][tx * 4]);
#pragma unroll
            for (int i = 0; i < 4; i++) {
                float4 a = *(const float4*)(&As1[ty * 4 + i][ku]);
                fma_row(acc1[i], a, b0, b1, b2, b3);
                if (DUAL) {
                    float4 a2 = *(const float4*)(&As2[ty * 4 + i][ku]);
                    fma_row(acc2[i], a2, b0, b1, b2, b3);
                }
            }
        }
    }

    float c0 = 1.0f, c1 = 0.0f;
    if (DUAL && cw) { c0 = cw[0]; c1 = cw[1]; }
    float* Pp = Pz + ((size_t)s * NROWS + r0) * 64;
#pragma unroll
    for (int i = 0; i < 4; i++) {
        int row = ty * 4 + i;
        float4 o;
        if (DUAL) {
            o.x = c0 * acc1[i][0] + c1 * acc2[i][0];
            o.y = c0 * acc1[i][1] + c1 * acc2[i][1];
            o.z = c0 * acc1[i][2] + c1 * acc2[i][2];
            o.w = c0 * acc1[i][3] + c1 * acc2[i][3];
        } else {
            o.x = acc1[i][0]; o.y = acc1[i][1]; o.z = acc1[i][2]; o.w = acc1[i][3];
        }
        *(float4*)(Pp + (size_t)row * 64 + tx * 4) = o;
    }
}

// out[z][i][j] = maybe_spike( sum_s P[z][s][i][j] + cb[0]*colsum[j] )
__global__ __launch_bounds__(256) void reduce_p(
    const float* __restrict__ P, float* __restrict__ out,
    const float* __restrict__ colsum, const float* __restrict__ cb,
    int S, int spike_flag, size_t bank_stride)
{
    const float* Pz = P + (size_t)blockIdx.z * bank_stride;
    size_t idx = (size_t)blockIdx.x * 256 + threadIdx.x;
    float v = 0.f;
    for (int s = 0; s < S; s++) v += Pz[(size_t)s * NROWS * 64 + idx];
    if (colsum) v += cb[0] * colsum[idx & 63];
    if (spike_flag) v = spikef(v);
    out[(size_t)blockIdx.z * NROWS * 64 + idx] = v;
}

// column sums of fe1/fe2 (for the conv-bias rank-1 term)
__global__ __launch_bounds__(256) void colsum_part(
    const float* __restrict__ fe1, const float* __restrict__ fe2,
    float* __restrict__ part)   // [2][96][64]
{
    const float* fe = blockIdx.z ? fe2 : fe1;
    int r0 = blockIdx.x * 64;
    int g = threadIdx.x >> 6, j = threadIdx.x & 63;
    float v = 0.f;
    for (int i = g; i < 64; i += 4) v += fe[(size_t)(r0 + i) * 64 + j];
    __shared__ float red[4][64];
    red[g][j] = v;
    __syncthreads();
    if (g == 0)
        part[((size_t)blockIdx.z * 96 + blockIdx.x) * 64 + j] =
            red[0][j] + red[1][j] + red[2][j] + red[3][j];
}

__global__ __launch_bounds__(128) void colsum_final(const float* __restrict__ part,
                                                    float* __restrict__ colsum)
{
    int z = threadIdx.x >> 6, j = threadIdx.x & 63;
    float v = 0.f;
    for (int b = 0; b < 96; b++) v += part[((size_t)z * 96 + b) * 64 + j];
    colsum[z * 64 + j] = v;
}

// q/k/v = spike(x @ W) for three weights, fused. grid 96 (64-row tiles)
__global__ __launch_bounds__(256) void qkv_kernel(
    const float* __restrict__ x, const float* __restrict__ wq,
    const float* __restrict__ wk, const float* __restrict__ wv,
    float* __restrict__ qo, float* __restrict__ ko, float* __restrict__ vo)
{
    __shared__ __align__(16) float xt[64 * 64];    // xt[kk*64 + row]
    __shared__ __align__(16) float wqs[64 * 64];
    __shared__ __align__(16) float wks[64 * 64];
    __shared__ __align__(16) float wvs[64 * 64];
    int tid = threadIdx.x;
    int r0 = blockIdx.x * 64;
#pragma unroll
    for (int i = 0; i < 4; i++) {
        int qd = tid + i * 256;
        int row = qd >> 4, cq = (qd & 15) * 4;
        float4 xv = *(const float4*)(x + (size_t)(r0 + row) * 64 + cq);
        xt[(cq + 0) * 64 + row] = xv.x;
        xt[(cq + 1) * 64 + row] = xv.y;
        xt[(cq + 2) * 64 + row] = xv.z;
        xt[(cq + 3) * 64 + row] = xv.w;
        *(float4*)&wqs[qd * 4] = *(const float4*)(wq + (size_t)qd * 4);
        *(float4*)&wks[qd * 4] = *(const float4*)(wk + (size_t)qd * 4);
        *(float4*)&wvs[qd * 4] = *(const float4*)(wv + (size_t)qd * 4);
    }
    __syncthreads();
    int ty = tid >> 4, tx = tid & 15;
    float aq[4][4] = {}, ak[4][4] = {}, av[4][4] = {};
    for (int kk = 0; kk < 64; kk++) {
        float4 a = *(const float4*)&xt[kk * 64 + 4 * ty];
        float4 bq = *(const float4*)&wqs[kk * 64 + 4 * tx];
        float4 bk = *(const float4*)&wks[kk * 64 + 4 * tx];
        float4 bv = *(const float4*)&wvs[kk * 64 + 4 * tx];
        fma_outer(aq, a, bq);
        fma_outer(ak, a, bk);
        fma_outer(av, a, bv);
    }
#pragma unroll
    for (int i = 0; i < 4; i++) {
        size_t off = (size_t)(r0 + 4 * ty + i) * 64 + 4 * tx;
        float4 oq, ok, ov;
        oq.x = spikef(aq[i][0]); oq.y = spikef(aq[i][1]); oq.z = spikef(aq[i][2]); oq.w = spikef(aq[i][3]);
        ok.x = spikef(ak[i][0]); ok.y = spikef(ak[i][1]); ok.z = spikef(ak[i][2]); ok.w = spikef(ak[i][3]);
        ov.x = spikef(av[i][0]); ov.y = spikef(av[i][1]); ov.z = spikef(av[i][2]); ov.w = spikef(av[i][3]);
        *(float4*)(qo + off) = oq;
        *(float4*)(ko + off) = ok;
        *(float4*)(vo + off) = ov;
    }
}

// partial kv[h,d,e] over 64-row chunks. grid 96.
__global__ __launch_bounds__(256) void kv_part_kernel(
    const float* __restrict__ k, const float* __restrict__ v, float* __restrict__ kvp)
{
    __shared__ __align__(16) float ks[64 * 64];
    __shared__ __align__(16) float vs[64 * 64];
    int tid = threadIdx.x;
    int r0 = blockIdx.x * 64;
#pragma unroll
    for (int i = 0; i < 4; i++) {
        int qd = tid + i * 256;
        int row = qd >> 4, cq = (qd & 15) * 4;
        *(float4*)&ks[qd * 4] = *(const float4*)(k + (size_t)(r0 + row) * 64 + cq);
        *(float4*)&vs[qd * 4] = *(const float4*)(v + (size_t)(r0 + row) * 64 + cq);
    }
    __syncthreads();
#pragma unroll
    for (int i = 0; i < 2; i++) {
        int ci = tid + i * 256;
        int h = ci >> 6, d = (ci >> 3) & 7, e = ci & 7;
        float acc = 0.f;
        for (int n = 0; n < 64; n++)
            acc += ks[n * 64 + h * 8 + d] * vs[n * 64 + h * 8 + e];
        kvp[(size_t)blockIdx.x * 512 + ci] = acc;
    }
}

// o = (q . kv) * 0.25 ; emb = x + o @ wp. grid 96.
__global__ __launch_bounds__(256) void attn_final(
    const float* __restrict__ q, const float* __restrict__ kvp,
    const float* __restrict__ wp, const float* __restrict__ x,
    float* __restrict__ emb)
{
    __shared__ __align__(16) float qs[64 * 64];
    __shared__ __align__(16) float ot[64 * 64];
    __shared__ __align__(16) float wps[64 * 64];
    __shared__ __align__(16) float kvs[512];
    int tid = threadIdx.x;
    int r0 = blockIdx.x * 64;
#pragma unroll
    for (int i = 0; i < 2; i++) {
        int ci = tid + i * 256;
        float vsum = 0.f;
        for (int ch = 0; ch < 96; ch++) vsum += kvp[(size_t)ch * 512 + ci];
        kvs[ci] = vsum;
    }
#pragma unroll
    for (int i = 0; i < 4; i++) {
        int qd = tid + i * 256;
        int row = qd >> 4, cq = (qd & 15) * 4;
        *(float4*)&qs[qd * 4] = *(const float4*)(q + (size_t)(r0 + row) * 64 + cq);
        *(float4*)&wps[qd * 4] = *(const float4*)(wp + (size_t)qd * 4);
    }
    __syncthreads();
    int ty = tid >> 4, tx = tid & 15;
    float o[4][4];
#pragma unroll
    for (int i = 0; i < 4; i++)
#pragma unroll
        for (int j = 0; j < 4; j++) {
            int r = 4 * ty + i, c = 4 * tx + j;
            int h = c >> 3, e = c & 7;
            float acc = 0.f;
#pragma unroll
            for (int d = 0; d < 8; d++)
                acc += qs[r * 64 + h * 8 + d] * kvs[h * 64 + d * 8 + e];
            o[i][j] = acc * 0.25f;
        }
#pragma unroll
    for (int i = 0; i < 4; i++)
#pragma unroll
        for (int j = 0; j < 4; j++)
            ot[(4 * tx + j) * 64 + (4 * ty + i)] = o[i][j];
    __syncthreads();
    float acc2[4][4] = {};
    for (int c = 0; c < 64; c++) {
        float4 a = *(const float4*)&ot[c * 64 + 4 * ty];
        float4 b = *(const float4*)&wps[c * 64 + 4 * tx];
        fma_outer(acc2, a, b);
    }
#pragma unroll
    for (int i = 0; i < 4; i++) {
        size_t off = (size_t)(r0 + 4 * ty + i) * 64 + 4 * tx;
        float4 xv = *(const float4*)(x + off);
        float4 ov;
        ov.x = xv.x + acc2[i][0];
        ov.y = xv.y + acc2[i][1];
        ov.z = xv.z + acc2[i][2];
        ov.w = xv.w + acc2[i][3];
        *(float4*)(emb + off) = ov;
    }
}

// comb = spike(cat @ fc1 + b1) @ fc2 + b2 ; scomb = spike(comb). grid 96.
__global__ __launch_bounds__(256) void comb_kernel(
    const float* __restrict__ emb1, const float* __restrict__ emb2,
    const float* __restrict__ fc1w, const float* __restrict__ fc1b,
    const float* __restrict__ fc2w, const float* __restrict__ fc2b,
    float* __restrict__ comb, float* __restrict__ scomb)
{
    __shared__ __align__(16) float ct[128 * 64];  // cat transposed [kk][row]
    __shared__ __align__(16) float fs[128 * 64];  // fc1 weights
    int tid = threadIdx.x;
    int r0 = blockIdx.x * 64;
#pragma unroll
    for (int i = 0; i < 4; i++) {
        int qd = tid + i * 256;
        int row = qd >> 4, cq = (qd & 15) * 4;
        float4 e1 = *(const float4*)(emb1 + (size_t)(r0 + row) * 64 + cq);
        float4 e2 = *(const float4*)(emb2 + (size_t)(r0 + row) * 64 + cq);
        ct[(cq + 0) * 64 + row] = e1.x;
        ct[(cq + 1) * 64 + row] = e1.y;
        ct[(cq + 2) * 64 + row] = e1.z;
        ct[(cq + 3) * 64 + row] = e1.w;
        ct[(64 + cq + 0) * 64 + row] = e2.x;
        ct[(64 + cq + 1) * 64 + row] = e2.y;
        ct[(64 + cq + 2) * 64 + row] = e2.z;
        ct[(64 + cq + 3) * 64 + row] = e2.w;
    }
#pragma unroll
    for (int i = 0; i < 8; i++) {
        int qd = tid + i * 256;
        *(float4*)&fs[qd * 4] = *(const float4*)(fc1w + (size_t)qd * 4);
    }
    __syncthreads();
    int ty = tid >> 4, tx = tid & 15;
    float acc[4][4] = {};
    for (int kk = 0; kk < 128; kk++) {
        float4 a = *(const float4*)&ct[kk * 64 + 4 * ty];
        float4 b = *(const float4*)&fs[kk * 64 + 4 * tx];
        fma_outer(acc, a, b);
    }
    float h[4][4];
#pragma unroll
    for (int j = 0; j < 4; j++) {
        float b1 = fc1b[4 * tx + j];
#pragma unroll
        for (int i = 0; i < 4; i++) h[i][j] = spikef(acc[i][j] + b1);
    }
    __syncthreads();
#pragma unroll
    for (int i = 0; i < 4; i++)
#pragma unroll
        for (int j = 0; j < 4; j++)
            ct[(4 * tx + j) * 64 + (4 * ty + i)] = h[i][j];
#pragma unroll
    for (int i = 0; i < 4; i++) {
        int qd = tid + i * 256;
        *(float4*)&fs[qd * 4] = *(const float4*)(fc2w + (size_t)qd * 4);
    }
    __syncthreads();
    float a2[4][4] = {};
    for (int c = 0; c < 64; c++) {
        float4 a = *(const float4*)&ct[c * 64 + 4 * ty];
        float4 b = *(const float4*)&fs[c * 64 + 4 * tx];
        fma_outer(a2, a, b);
    }
#pragma unroll
    for (int i = 0; i < 4; i++) {
        size_t off = (size_t)(r0 + 4 * ty + i) * 64 + 4 * tx;
        float4 cv, sv;
        float b20 = fc2b[4 * tx + 0], b21 = fc2b[4 * tx + 1];
        float b22 = fc2b[4 * tx + 2], b23 = fc2b[4 * tx + 3];
        cv.x = a2[i][0] + b20; cv.y = a2[i][1] + b21;
        cv.z = a2[i][2] + b22; cv.w = a2[i][3] + b23;
        sv.x = spikef(cv.x); sv.y = spikef(cv.y); sv.z = spikef(cv.z); sv.w = spikef(cv.w);
        *(float4*)(comb + off) = cv;
        *(float4*)(scomb + off) = sv;
    }
}

// out = spike(g @ W), W: 64 x KO. grid (96, ceil(KO/128))
__global__ __launch_bounds__(256) void recon_kernel(
    const float* __restrict__ g, const float* __restrict__ W,
    float* __restrict__ out, int KO)
{
    __shared__ __align__(16) float gt[64 * 64];    // gt[kk][row]
    __shared__ __align__(16) float wsh[64 * 128];
    int tid = threadIdx.x;
    int r0 = blockIdx.x * 64;
    int c0 = blockIdx.y * 128;
#pragma unroll
    for (int i = 0; i < 4; i++) {
        int qd = tid + i * 256;
        int row = qd >> 4, cq = (qd & 15) * 4;
        float4 gv = *(const float4*)(g + (size_t)(r0 + row) * 64 + cq);
        gt[(cq + 0) * 64 + row] = gv.x;
        gt[(cq + 1) * 64 + row] = gv.y;
        gt[(cq + 2) * 64 + row] = gv.z;
        gt[(cq + 3) * 64 + row] = gv.w;
    }
#pragma unroll
    for (int i = 0; i < 8; i++) {
        int qd = tid + i * 256;
        int row = qd >> 5, cq = (qd & 31) * 4;
        float4 wv = make_float4(0.f, 0.f, 0.f, 0.f);
        if (c0 + cq + 4 <= KO) wv = *(const float4*)(W + (size_t)row * KO + c0 + cq);
        *(float4*)&wsh[row * 128 + cq] = wv;
    }
    __syncthreads();
    int ty = tid >> 5, tx = tid & 31;   // rows 8*ty.., cols 4*tx
    float accA[4][4] = {};
    float accB[4][4] = {};
    for (int kk = 0; kk < 64; kk++) {
        float4 a0 = *(const float4*)&gt[kk * 64 + 8 * ty];
        float4 a1 = *(const float4*)&gt[kk * 64 + 8 * ty + 4];
        float4 b = *(const float4*)&wsh[kk * 128 + 4 * tx];
        fma_outer(accA, a0, b);
        fma_outer(accB, a1, b);
    }
    if (c0 + 4 * tx < KO) {
#pragma unroll
        for (int i = 0; i < 8; i++) {
            int r = r0 + 8 * ty + i;
            const float (&ac)[4] = (i < 4) ? accA[i] : accB[i - 4];
            float4 ov;
            ov.x = spikef(ac[0]); ov.y = spikef(ac[1]);
            ov.z = spikef(ac[2]); ov.w = spikef(ac[3]);
            *(float4*)(out + (size_t)r * KO + c0 + 4 * tx) = ov;
        }
    }
}

extern "C" void kernel_launch(void* const* d_in, const int* in_sizes, int n_in,
                              void* d_out, int out_size, void* d_ws, size_t ws_size,
                              hipStream_t stream)
{
    (void)in_sizes; (void)n_in; (void)out_size; (void)ws_size;

    const float* F1    = (const float*)d_in[0];
    const float* F2    = (const float*)d_in[1];
    const float* Asp1  = (const float*)d_in[2];
    const float* Aft1  = (const float*)d_in[3];
    const float* Asp2  = (const float*)d_in[4];
    const float* Aft2  = (const float*)d_in[5];
    const float* c1w   = (const float*)d_in[6];
    const float* c1b   = (const float*)d_in[7];
    const float* c2w   = (const float*)d_in[8];
    const float* c2b   = (const float*)d_in[9];
    const float* Wenc1 = (const float*)d_in[10];
    const float* Wq1   = (const float*)d_in[11];
    const float* Wk1   = (const float*)d_in[12];
    const float* Wv1   = (const float*)d_in[13];
    const float* Wp1   = (const float*)d_in[14];
    const float* Wenc2 = (const float*)d_in[15];
    const float* Wq2   = (const float*)d_in[16];
    const float* Wk2   = (const float*)d_in[17];
    const float* Wv2   = (const float*)d_in[18];
    const float* Wp2   = (const float*)d_in[19];
    const float* FC1w  = (const float*)d_in[20];
    const float* FC1b  = (const float*)d_in[21];
    const float* FC2w  = (const float*)d_in[22];
    const float* FC2b  = (const float*)d_in[23];
    const float* Wd1   = (const float*)d_in[24];
    const float* Wd2   = (const float*)d_in[25];

    float* out = (float*)d_out;
    const size_t NC = (size_t)NROWS * 64;
    float* emb1  = out;
    float* emb2  = out + NC;
    float* scomb = out + 2 * NC;
    float* rec1  = out + 3 * NC;
    float* rec2  = out + 3 * NC + (size_t)NROWS * DIN1;

    float* ws   = (float*)d_ws;
    float* fe1  = ws;
    float* fe2  = ws + NC;
    float* x1   = ws + 2 * NC;
    float* x2   = ws + 3 * NC;
    float* qb   = ws + 4 * NC;
    float* kb   = ws + 5 * NC;
    float* vb   = ws + 6 * NC;
    float* comb = ws + 7 * NC;
    float* g    = ws + 8 * NC;           // 2 banks
    float* csp  = ws + 10 * NC;          // [2][96][64]
    float* csum = csp + 2 * 96 * 64;     // [2][64]
    float* kvp  = csum + 128;            // [96][512]
    float* P    = kvp + 96 * 512;        // [2][8][NROWS][64]
    const size_t PBANK = 8 * NC;

    // feature embeddings
    gemm_dual<false><<<dim3(96, 8, 1), 256, 0, stream>>>(F1, F1, nullptr, Wenc1, nullptr, P, DIN1, DIN1, 375, 0);
    reduce_p<<<dim3(1536, 1, 1), 256, 0, stream>>>(P, fe1, nullptr, nullptr, 8, 0, 0);
    gemm_dual<false><<<dim3(96, 8, 1), 256, 0, stream>>>(F2, F2, nullptr, Wenc2, nullptr, P, DIN2, DIN2, 64, 0);
    reduce_p<<<dim3(1536, 1, 1), 256, 0, stream>>>(P, fe2, nullptr, nullptr, 8, 0, 0);
    colsum_part<<<dim3(96, 1, 2), 256, 0, stream>>>(fe1, fe2, csp);
    colsum_final<<<dim3(1, 1, 1), 128, 0, stream>>>(csp, csum);

    // encoder 1
    gemm_dual<true><<<dim3(96, 8, 1), 256, 0, stream>>>(Asp1, Asp1, Aft1, fe1, c1w, P, NROWS, NROWS, 768, 0);
    reduce_p<<<dim3(1536, 1, 1), 256, 0, stream>>>(P, x1, csum, c1b, 8, 1, 0);
    qkv_kernel<<<96, 256, 0, stream>>>(x1, Wq1, Wk1, Wv1, qb, kb, vb);
    kv_part_kernel<<<96, 256, 0, stream>>>(kb, vb, kvp);
    attn_final<<<96, 256, 0, stream>>>(qb, kvp, Wp1, x1, emb1);

    // encoder 2
    gemm_dual<true><<<dim3(96, 8, 1), 256, 0, stream>>>(Asp2, Asp2, Aft2, fe2, c2w, P, NROWS, NROWS, 768, 0);
    reduce_p<<<dim3(1536, 1, 1), 256, 0, stream>>>(P, x2, csum + 64, c2b, 8, 1, 0);
    qkv_kernel<<<96, 256, 0, stream>>>(x2, Wq2, Wk2, Wv2, qb, kb, vb);
    kv_part_kernel<<<96, 256, 0, stream>>>(kb, vb, kvp);
    attn_final<<<96, 256, 0, stream>>>(qb, kvp, Wp2, x2, emb2);

    // MLP combine
    comb_kernel<<<96, 256, 0, stream>>>(emb1, emb2, FC1w, FC1b, FC2w, FC2b, comb, scomb);

    // decoders: g = adj_spatial @ comb (reassociated), then recon = spike(g @ w_dec)
    gemm_dual<false><<<dim3(96, 8, 2), 256, 0, stream>>>(Asp1, Asp2, nullptr, comb, nullptr, P, NROWS, NROWS, 768, PBANK);
    reduce_p<<<dim3(1536, 1, 2), 256, 0, stream>>>(P, g, nullptr, nullptr, 8, 0, PBANK);
    recon_kernel<<<dim3(96, 24, 1), 256, 0, stream>>>(g, Wd1, rec1, DIN1);
    recon_kernel<<<dim3(96, 4, 1), 256, 0, stream>>>(g + NC, Wd2, rec2, DIN2);
}

// Round 2
// 924.289 us; speedup vs baseline: 1.9309x; 1.9309x over previous
//
#include <hip/hip_runtime.h>

#define NROWS 6144
#define DIN1 3000
#define DIN2 512

typedef __attribute__((ext_vector_type(8))) short short8;
typedef __attribute__((ext_vector_type(4))) float floatx4;

__device__ __forceinline__ float spikef(float y) {
    float t = 4.0f * y;
    t = fminf(fmaxf(t, 0.0f), 4.0f);
    return floorf(t + 0.5f) * 0.25f;
}

__device__ __forceinline__ unsigned short f2bf(float f) {
    union { float f; unsigned u; } c; c.f = f;
    unsigned r = c.u + 0x7fffu + ((c.u >> 16) & 1u);
    return (unsigned short)(r >> 16);
}

__device__ __forceinline__ void fma_outer(float (&acc)[4][4], const float4& a, const float4& b) {
    const float av[4] = {a.x, a.y, a.z, a.w};
    const float bv[4] = {b.x, b.y, b.z, b.w};
#pragma unroll
    for (int i = 0; i < 4; i++)
#pragma unroll
        for (int j = 0; j < 4; j++)
            acc[i][j] += av[i] * bv[j];
}

// ---------------------------------------------------------------------------
// bf16-MFMA split-K GEMM: P[z][s] += A @ Bt^T
//   A: [NROWS x lda] fp32 (COMBINE: c0*A1 + c1*A2 fused at staging;
//      else z selects A1 / A1b)
//   Bt: [64 x ldb] bf16, n-major, k contiguous (zero-padded to ldb)
// Block: 128 rows x 64 cols, BK=64, 256 threads (4 waves).
// ---------------------------------------------------------------------------
template <bool COMBINE>
__global__ __launch_bounds__(256) void gemm_bf16(
    const float* __restrict__ A1, const float* __restrict__ A1b,
    const float* __restrict__ A2, const float* __restrict__ cw,
    const unsigned short* __restrict__ Bt, float* __restrict__ P,
    int K, int lda, int kchunk, int ldb, size_t bank_stride)
{
    __shared__ __align__(16) unsigned short Asb[128][72];
    __shared__ __align__(16) unsigned short Bts[64][72];

    const float* A = COMBINE ? A1 : (blockIdx.z ? A1b : A1);
    float c0 = 1.f, c1 = 0.f;
    if (COMBINE) { c0 = cw[0]; c1 = cw[1]; }

    int t = threadIdx.x;
    int r0 = blockIdx.x * 128;
    int s = blockIdx.y;
    int k0 = s * kchunk;
    int kend = min(K, k0 + kchunk);

    int w = t >> 6, lane = t & 63, quad = lane >> 4, l15 = lane & 15;
    int ar = t >> 4, ak = (t & 15) * 4;   // A staging: 16 rows/pass, 4 k each
    int bn = t >> 2, bk = (t & 3) * 16;   // B staging: 64 n, 16 k each

    floatx4 zf = {0.f, 0.f, 0.f, 0.f};
    floatx4 acc[2][4];
#pragma unroll
    for (int m = 0; m < 2; m++)
#pragma unroll
        for (int c = 0; c < 4; c++) acc[m][c] = zf;

    for (int kb = k0; kb < kend; kb += 64) {
        __syncthreads();
        // ---- stage B (already bf16, padded): 64 x 64 ----
        *(uint4*)&Bts[bn][bk]     = *(const uint4*)&Bt[(size_t)bn * ldb + kb + bk];
        *(uint4*)&Bts[bn][bk + 8] = *(const uint4*)&Bt[(size_t)bn * ldb + kb + bk + 8];
        // ---- stage A (fp32 -> bf16): 128 x 64 ----
#pragma unroll
        for (int p = 0; p < 8; p++) {
            int row = p * 16 + ar;
            int k = kb + ak;
            const float* ap = A + (size_t)(r0 + row) * lda;
            float4 v = make_float4(0.f, 0.f, 0.f, 0.f);
            if (k + 4 <= kend) {
                v = *(const float4*)(ap + k);
            } else if (k < kend) {
                float* vp = (float*)&v;
                for (int j = 0; j < 4; j++)
                    if (k + j < kend) vp[j] = ap[k + j];
            }
            if (COMBINE) {
                const float* ap2 = A2 + (size_t)(r0 + row) * lda;
                float4 v2 = make_float4(0.f, 0.f, 0.f, 0.f);
                if (k + 4 <= kend) {
                    v2 = *(const float4*)(ap2 + k);
                } else if (k < kend) {
                    float* vp = (float*)&v2;
                    for (int j = 0; j < 4; j++)
                        if (k + j < kend) vp[j] = ap2[k + j];
                }
                v.x = c0 * v.x + c1 * v2.x;
                v.y = c0 * v.y + c1 * v2.y;
                v.z = c0 * v.z + c1 * v2.z;
                v.w = c0 * v.w + c1 * v2.w;
            }
            unsigned lo = (unsigned)f2bf(v.x) | ((unsigned)f2bf(v.y) << 16);
            unsigned hi = (unsigned)f2bf(v.z) | ((unsigned)f2bf(v.w) << 16);
            *(uint2*)&Asb[row][ak] = make_uint2(lo, hi);
        }
        __syncthreads();
        // ---- MFMA: each wave 32 rows x 64 cols ----
#pragma unroll
        for (int ks = 0; ks < 2; ks++) {
            short8 a0 = *(const short8*)&Asb[w * 32 + l15][ks * 32 + quad * 8];
            short8 a1 = *(const short8*)&Asb[w * 32 + 16 + l15][ks * 32 + quad * 8];
#pragma unroll
            for (int c = 0; c < 4; c++) {
                short8 b = *(const short8*)&Bts[c * 16 + l15][ks * 32 + quad * 8];
                acc[0][c] = __builtin_amdgcn_mfma_f32_16x16x32_bf16(a0, b, acc[0][c], 0, 0, 0);
                acc[1][c] = __builtin_amdgcn_mfma_f32_16x16x32_bf16(a1, b, acc[1][c], 0, 0, 0);
            }
        }
    }

    // epilogue: C/D layout col=lane&15, row=quad*4+reg
    float* Pp = P + (size_t)blockIdx.z * bank_stride + ((size_t)s * NROWS + r0) * 64;
#pragma unroll
    for (int m = 0; m < 2; m++)
#pragma unroll
        for (int c = 0; c < 4; c++)
#pragma unroll
            for (int j = 0; j < 4; j++) {
                int row = w * 32 + m * 16 + quad * 4 + j;
                Pp[(size_t)row * 64 + c * 16 + l15] = acc[m][c][j];
            }
}

// W [K][64] fp32 -> out [64][ldb] bf16 (transposed, zero-padded to ldb)
__global__ __launch_bounds__(256) void cvt_wT(const float* __restrict__ W,
                                              unsigned short* __restrict__ out,
                                              int K, int ldb)
{
    int kk = blockIdx.x * 64 + (threadIdx.x & 63);
    int ng = threadIdx.x >> 6;
    for (int n = ng; n < 64; n += 4)
        out[(size_t)n * ldb + kk] = (kk < K) ? f2bf(W[(size_t)kk * 64 + n]) : (unsigned short)0;
}

// in [NROWS][64] fp32 -> out [64][NROWS] bf16 (transposed)
__global__ __launch_bounds__(256) void tcvt(const float* __restrict__ in,
                                            unsigned short* __restrict__ out)
{
    int r0 = blockIdx.x * 64;
    int k = threadIdx.x & 63;
    int ng = threadIdx.x >> 6;
    for (int n = ng; n < 64; n += 4)
        out[(size_t)n * NROWS + r0 + k] = f2bf(in[(size_t)(r0 + k) * 64 + n]);
}

// out[z][i][j] = maybe_spike( sum_s P[z][s][i][j] + cb[0]*colsum[j] )
__global__ __launch_bounds__(256) void reduce_p(
    const float* __restrict__ P, float* __restrict__ out,
    const float* __restrict__ colsum, const float* __restrict__ cb,
    int S, int spike_flag, size_t bank_stride)
{
    const float* Pz = P + (size_t)blockIdx.z * bank_stride;
    size_t idx = (size_t)blockIdx.x * 256 + threadIdx.x;
    float v = 0.f;
    for (int s = 0; s < S; s++) v += Pz[(size_t)s * NROWS * 64 + idx];
    if (colsum) v += cb[0] * colsum[idx & 63];
    if (spike_flag) v = spikef(v);
    out[(size_t)blockIdx.z * NROWS * 64 + idx] = v;
}

// column sums of fe1/fe2 (rank-1 conv-bias term)
__global__ __launch_bounds__(256) void colsum_part(
    const float* __restrict__ fe1, const float* __restrict__ fe2,
    float* __restrict__ part)   // [2][96][64]
{
    const float* fe = blockIdx.z ? fe2 : fe1;
    int r0 = blockIdx.x * 64;
    int g = threadIdx.x >> 6, j = threadIdx.x & 63;
    float v = 0.f;
    for (int i = g; i < 64; i += 4) v += fe[(size_t)(r0 + i) * 64 + j];
    __shared__ float red[4][64];
    red[g][j] = v;
    __syncthreads();
    if (g == 0)
        part[((size_t)blockIdx.z * 96 + blockIdx.x) * 64 + j] =
            red[0][j] + red[1][j] + red[2][j] + red[3][j];
}

__global__ __launch_bounds__(128) void colsum_final(const float* __restrict__ part,
                                                    float* __restrict__ colsum)
{
    int z = threadIdx.x >> 6, j = threadIdx.x & 63;
    float v = 0.f;
    for (int b = 0; b < 96; b++) v += part[((size_t)z * 96 + b) * 64 + j];
    colsum[z * 64 + j] = v;
}

// q/k/v = spike(x @ W) for three weights, fused. grid 96 (64-row tiles)
__global__ __launch_bounds__(256) void qkv_kernel(
    const float* __restrict__ x, const float* __restrict__ wq,
    const float* __restrict__ wk, const float* __restrict__ wv,
    float* __restrict__ qo, float* __restrict__ ko, float* __restrict__ vo)
{
    __shared__ __align__(16) float xt[64 * 64];
    __shared__ __align__(16) float wqs[64 * 64];
    __shared__ __align__(16) float wks[64 * 64];
    __shared__ __align__(16) float wvs[64 * 64];
    int tid = threadIdx.x;
    int r0 = blockIdx.x * 64;
#pragma unroll
    for (int i = 0; i < 4; i++) {
        int qd = tid + i * 256;
        int row = qd >> 4, cq = (qd & 15) * 4;
        float4 xv = *(const float4*)(x + (size_t)(r0 + row) * 64 + cq);
        xt[(cq + 0) * 64 + row] = xv.x;
        xt[(cq + 1) * 64 + row] = xv.y;
        xt[(cq + 2) * 64 + row] = xv.z;
        xt[(cq + 3) * 64 + row] = xv.w;
        *(float4*)&wqs[qd * 4] = *(const float4*)(wq + (size_t)qd * 4);
        *(float4*)&wks[qd * 4] = *(const float4*)(wk + (size_t)qd * 4);
        *(float4*)&wvs[qd * 4] = *(const float4*)(wv + (size_t)qd * 4);
    }
    __syncthreads();
    int ty = tid >> 4, tx = tid & 15;
    float aq[4][4] = {}, ak[4][4] = {}, av[4][4] = {};
    for (int kk = 0; kk < 64; kk++) {
        float4 a = *(const float4*)&xt[kk * 64 + 4 * ty];
        float4 bq = *(const float4*)&wqs[kk * 64 + 4 * tx];
        float4 bk = *(const float4*)&wks[kk * 64 + 4 * tx];
        float4 bv = *(const float4*)&wvs[kk * 64 + 4 * tx];
        fma_outer(aq, a, bq);
        fma_outer(ak, a, bk);
        fma_outer(av, a, bv);
    }
#pragma unroll
    for (int i = 0; i < 4; i++) {
        size_t off = (size_t)(r0 + 4 * ty + i) * 64 + 4 * tx;
        float4 oq, ok, ov;
        oq.x = spikef(aq[i][0]); oq.y = spikef(aq[i][1]); oq.z = spikef(aq[i][2]); oq.w = spikef(aq[i][3]);
        ok.x = spikef(ak[i][0]); ok.y = spikef(ak[i][1]); ok.z = spikef(ak[i][2]); ok.w = spikef(ak[i][3]);
        ov.x = spikef(av[i][0]); ov.y = spikef(av[i][1]); ov.z = spikef(av[i][2]); ov.w = spikef(av[i][3]);
        *(float4*)(qo + off) = oq;
        *(float4*)(ko + off) = ok;
        *(float4*)(vo + off) = ov;
    }
}

// partial kv[h,d,e] over 64-row chunks. grid 96.
__global__ __launch_bounds__(256) void kv_part_kernel(
    const float* __restrict__ k, const float* __restrict__ v, float* __restrict__ kvp)
{
    __shared__ __align__(16) float ks[64 * 64];
    __shared__ __align__(16) float vs[64 * 64];
    int tid = threadIdx.x;
    int r0 = blockIdx.x * 64;
#pragma unroll
    for (int i = 0; i < 4; i++) {
        int qd = tid + i * 256;
        int row = qd >> 4, cq = (qd & 15) * 4;
        *(float4*)&ks[qd * 4] = *(const float4*)(k + (size_t)(r0 + row) * 64 + cq);
        *(float4*)&vs[qd * 4] = *(const float4*)(v + (size_t)(r0 + row) * 64 + cq);
    }
    __syncthreads();
#pragma unroll
    for (int i = 0; i < 2; i++) {
        int ci = tid + i * 256;
        int h = ci >> 6, d = (ci >> 3) & 7, e = ci & 7;
        float acc = 0.f;
        for (int n = 0; n < 64; n++)
            acc += ks[n * 64 + h * 8 + d] * vs[n * 64 + h * 8 + e];
        kvp[(size_t)blockIdx.x * 512 + ci] = acc;
    }
}

// o = (q . kv) * 0.25 ; emb = x + o @ wp. grid 96.
__global__ __launch_bounds__(256) void attn_final(
    const float* __restrict__ q, const float* __restrict__ kvp,
    const float* __restrict__ wp, const float* __restrict__ x,
    float* __restrict__ emb)
{
    __shared__ __align__(16) float qs[64 * 64];
    __shared__ __align__(16) float ot[64 * 64];
    __shared__ __align__(16) float wps[64 * 64];
    __shared__ __align__(16) float kvs[512];
    int tid = threadIdx.x;
    int r0 = blockIdx.x * 64;
#pragma unroll
    for (int i = 0; i < 2; i++) {
        int ci = tid + i * 256;
        float vsum = 0.f;
        for (int ch = 0; ch < 96; ch++) vsum += kvp[(size_t)ch * 512 + ci];
        kvs[ci] = vsum;
    }
#pragma unroll
    for (int i = 0; i < 4; i++) {
        int qd = tid + i * 256;
        int row = qd >> 4, cq = (qd & 15) * 4;
        *(float4*)&qs[qd * 4] = *(const float4*)(q + (size_t)(r0 + row) * 64 + cq);
        *(float4*)&wps[qd * 4] = *(const float4*)(wp + (size_t)qd * 4);
    }
    __syncthreads();
    int ty = tid >> 4, tx = tid & 15;
    float o[4][4];
#pragma unroll
    for (int i = 0; i < 4; i++)
#pragma unroll
        for (int j = 0; j < 4; j++) {
            int r = 4 * ty + i, c = 4 * tx + j;
            int h = c >> 3, e = c & 7;
            float acc = 0.f;
#pragma unroll
            for (int d = 0; d < 8; d++)
                acc += qs[r * 64 + h * 8 + d] * kvs[h * 64 + d * 8 + e];
            o[i][j] = acc * 0.25f;
        }
#pragma unroll
    for (int i = 0; i < 4; i++)
#pragma unroll
        for (int j = 0; j < 4; j++)
            ot[(4 * tx + j) * 64 + (4 * ty + i)] = o[i][j];
    __syncthreads();
    float acc2[4][4] = {};
    for (int c = 0; c < 64; c++) {
        float4 a = *(const float4*)&ot[c * 64 + 4 * ty];
        float4 b = *(const float4*)&wps[c * 64 + 4 * tx];
        fma_outer(acc2, a, b);
    }
#pragma unroll
    for (int i = 0; i < 4; i++) {
        size_t off = (size_t)(r0 + 4 * ty + i) * 64 + 4 * tx;
        float4 xv = *(const float4*)(x + off);
        float4 ov;
        ov.x = xv.x + acc2[i][0];
        ov.y = xv.y + acc2[i][1];
        ov.z = xv.z + acc2[i][2];
        ov.w = xv.w + acc2[i][3];
        *(float4*)(emb + off) = ov;
    }
}

// comb = spike(cat @ fc1 + b1) @ fc2 + b2 ; scomb = spike(comb). grid 96.
__global__ __launch_bounds__(256) void comb_kernel(
    const float* __restrict__ emb1, const float* __restrict__ emb2,
    const float* __restrict__ fc1w, const float* __restrict__ fc1b,
    const float* __restrict__ fc2w, const float* __restrict__ fc2b,
    float* __restrict__ comb, float* __restrict__ scomb)
{
    __shared__ __align__(16) float ct[128 * 64];
    __shared__ __align__(16) float fs[128 * 64];
    int tid = threadIdx.x;
    int r0 = blockIdx.x * 64;
#pragma unroll
    for (int i = 0; i < 4; i++) {
        int qd = tid + i * 256;
        int row = qd >> 4, cq = (qd & 15) * 4;
        float4 e1 = *(const float4*)(emb1 + (size_t)(r0 + row) * 64 + cq);
        float4 e2 = *(const float4*)(emb2 + (size_t)(r0 + row) * 64 + cq);
        ct[(cq + 0) * 64 + row] = e1.x;
        ct[(cq + 1) * 64 + row] = e1.y;
        ct[(cq + 2) * 64 + row] = e1.z;
        ct[(cq + 3) * 64 + row] = e1.w;
        ct[(64 + cq + 0) * 64 + row] = e2.x;
        ct[(64 + cq + 1) * 64 + row] = e2.y;
        ct[(64 + cq + 2) * 64 + row] = e2.z;
        ct[(64 + cq + 3) * 64 + row] = e2.w;
    }
#pragma unroll
    for (int i = 0; i < 8; i++) {
        int qd = tid + i * 256;
        *(float4*)&fs[qd * 4] = *(const float4*)(fc1w + (size_t)qd * 4);
    }
    __syncthreads();
    int ty = tid >> 4, tx = tid & 15;
    float acc[4][4] = {};
    for (int kk = 0; kk < 128; kk++) {
        float4 a = *(const float4*)&ct[kk * 64 + 4 * ty];
        float4 b = *(const float4*)&fs[kk * 64 + 4 * tx];
        fma_outer(acc, a, b);
    }
    float h[4][4];
#pragma unroll
    for (int j = 0; j < 4; j++) {
        float b1 = fc1b[4 * tx + j];
#pragma unroll
        for (int i = 0; i < 4; i++) h[i][j] = spikef(acc[i][j] + b1);
    }
    __syncthreads();
#pragma unroll
    for (int i = 0; i < 4; i++)
#pragma unroll
        for (int j = 0; j < 4; j++)
            ct[(4 * tx + j) * 64 + (4 * ty + i)] = h[i][j];
#pragma unroll
    for (int i = 0; i < 4; i++) {
        int qd = tid + i * 256;
        *(float4*)&fs[qd * 4] = *(const float4*)(fc2w + (size_t)qd * 4);
    }
    __syncthreads();
    float a2[4][4] = {};
    for (int c = 0; c < 64; c++) {
        float4 a = *(const float4*)&ct[c * 64 + 4 * ty];
        float4 b = *(const float4*)&fs[c * 64 + 4 * tx];
        fma_outer(a2, a, b);
    }
#pragma unroll
    for (int i = 0; i < 4; i++) {
        size_t off = (size_t)(r0 + 4 * ty + i) * 64 + 4 * tx;
        float4 cv, sv;
        float b20 = fc2b[4 * tx + 0], b21 = fc2b[4 * tx + 1];
        float b22 = fc2b[4 * tx + 2], b23 = fc2b[4 * tx + 3];
        cv.x = a2[i][0] + b20; cv.y = a2[i][1] + b21;
        cv.z = a2[i][2] + b22; cv.w = a2[i][3] + b23;
        sv.x = spikef(cv.x); sv.y = spikef(cv.y); sv.z = spikef(cv.z); sv.w = spikef(cv.w);
        *(float4*)(comb + off) = cv;
        *(float4*)(scomb + off) = sv;
    }
}

// out = spike(g @ W), W: 64 x KO. grid (96, ceil(KO/128))
__global__ __launch_bounds__(256) void recon_kernel(
    const float* __restrict__ g, const float* __restrict__ W,
    float* __restrict__ out, int KO)
{
    __shared__ __align__(16) float gt[64 * 64];
    __shared__ __align__(16) float wsh[64 * 128];
    int tid = threadIdx.x;
    int r0 = blockIdx.x * 64;
    int c0 = blockIdx.y * 128;
#pragma unroll
    for (int i = 0; i < 4; i++) {
        int qd = tid + i * 256;
        int row = qd >> 4, cq = (qd & 15) * 4;
        float4 gv = *(const float4*)(g + (size_t)(r0 + row) * 64 + cq);
        gt[(cq + 0) * 64 + row] = gv.x;
        gt[(cq + 1) * 64 + row] = gv.y;
        gt[(cq + 2) * 64 + row] = gv.z;
        gt[(cq + 3) * 64 + row] = gv.w;
    }
#pragma unroll
    for (int i = 0; i < 8; i++) {
        int qd = tid + i * 256;
        int row = qd >> 5, cq = (qd & 31) * 4;
        float4 wv = make_float4(0.f, 0.f, 0.f, 0.f);
        if (c0 + cq + 4 <= KO) wv = *(const float4*)(W + (size_t)row * KO + c0 + cq);
        *(float4*)&wsh[row * 128 + cq] = wv;
    }
    __syncthreads();
    int ty = tid >> 5, tx = tid & 31;
    float accA[4][4] = {};
    float accB[4][4] = {};
    for (int kk = 0; kk < 64; kk++) {
        float4 a0 = *(const float4*)&gt[kk * 64 + 8 * ty];
        float4 a1 = *(const float4*)&gt[kk * 64 + 8 * ty + 4];
        float4 b = *(const float4*)&wsh[kk * 128 + 4 * tx];
        fma_outer(accA, a0, b);
        fma_outer(accB, a1, b);
    }
    if (c0 + 4 * tx < KO) {
#pragma unroll
        for (int i = 0; i < 8; i++) {
            int r = r0 + 8 * ty + i;
            const float (&ac)[4] = (i < 4) ? accA[i] : accB[i - 4];
            float4 ov;
            ov.x = spikef(ac[0]); ov.y = spikef(ac[1]);
            ov.z = spikef(ac[2]); ov.w = spikef(ac[3]);
            *(float4*)(out + (size_t)r * KO + c0 + 4 * tx) = ov;
        }
    }
}

extern "C" void kernel_launch(void* const* d_in, const int* in_sizes, int n_in,
                              void* d_out, int out_size, void* d_ws, size_t ws_size,
                              hipStream_t stream)
{
    (void)in_sizes; (void)n_in; (void)out_size; (void)ws_size;

    const float* F1    = (const float*)d_in[0];
    const float* F2    = (const float*)d_in[1];
    const float* Asp1  = (const float*)d_in[2];
    const float* Aft1  = (const float*)d_in[3];
    const float* Asp2  = (const float*)d_in[4];
    const float* Aft2  = (const float*)d_in[5];
    const float* c1w   = (const float*)d_in[6];
    const float* c1b   = (const float*)d_in[7];
    const float* c2w   = (const float*)d_in[8];
    const float* c2b   = (const float*)d_in[9];
    const float* Wenc1 = (const float*)d_in[10];
    const float* Wq1   = (const float*)d_in[11];
    const float* Wk1   = (const float*)d_in[12];
    const float* Wv1   = (const float*)d_in[13];
    const float* Wp1   = (const float*)d_in[14];
    const float* Wenc2 = (const float*)d_in[15];
    const float* Wq2   = (const float*)d_in[16];
    const float* Wk2   = (const float*)d_in[17];
    const float* Wv2   = (const float*)d_in[18];
    const float* Wp2   = (const float*)d_in[19];
    const float* FC1w  = (const float*)d_in[20];
    const float* FC1b  = (const float*)d_in[21];
    const float* FC2w  = (const float*)d_in[22];
    const float* FC2b  = (const float*)d_in[23];
    const float* Wd1   = (const float*)d_in[24];
    const float* Wd2   = (const float*)d_in[25];

    float* out = (float*)d_out;
    const size_t NC = (size_t)NROWS * 64;
    float* emb1  = out;
    float* emb2  = out + NC;
    float* scomb = out + 2 * NC;
    float* rec1  = out + 3 * NC;
    float* rec2  = out + 3 * NC + (size_t)NROWS * DIN1;

    float* ws   = (float*)d_ws;
    float* fe1  = ws;
    float* fe2  = ws + NC;
    float* x1   = ws + 2 * NC;
    float* x2   = ws + 3 * NC;
    float* qb   = ws + 4 * NC;
    float* kb   = ws + 5 * NC;
    float* vb   = ws + 6 * NC;
    float* comb = ws + 7 * NC;
    float* g    = ws + 8 * NC;            // 2 banks
    float* csp  = ws + 10 * NC;           // [2][96][64]
    float* csum = csp + 2 * 96 * 64;      // [2][64]
    float* kvp  = csum + 128;             // [96][512]
    float* P    = kvp + 96 * 512;         // up to 16 slices (or 2 banks x 8)
    const size_t PBANK = 8 * NC;
    unsigned short* WT1   = (unsigned short*)(P + 16 * NC);     // [64][3008]
    unsigned short* WT2   = WT1 + (size_t)64 * 3008;            // [64][512]
    unsigned short* feT1  = WT2 + (size_t)64 * 512;             // [64][6144]
    unsigned short* feT2  = feT1 + (size_t)64 * NROWS;
    unsigned short* combT = feT2 + (size_t)64 * NROWS;

    // weight transposes (bf16)
    cvt_wT<<<dim3(47, 1, 1), 256, 0, stream>>>(Wenc1, WT1, DIN1, 3008);
    cvt_wT<<<dim3(8, 1, 1), 256, 0, stream>>>(Wenc2, WT2, DIN2, 512);

    // feature embeddings
    gemm_bf16<false><<<dim3(48, 16, 1), 256, 0, stream>>>(
        F1, F1, nullptr, nullptr, WT1, P, DIN1, DIN1, 192, 3008, 0);
    reduce_p<<<dim3(1536, 1, 1), 256, 0, stream>>>(P, fe1, nullptr, nullptr, 16, 0, 0);
    gemm_bf16<false><<<dim3(48, 8, 1), 256, 0, stream>>>(
        F2, F2, nullptr, nullptr, WT2, P, DIN2, DIN2, 64, 512, 0);
    reduce_p<<<dim3(1536, 1, 1), 256, 0, stream>>>(P, fe2, nullptr, nullptr, 8, 0, 0);
    colsum_part<<<dim3(96, 1, 2), 256, 0, stream>>>(fe1, fe2, csp);
    colsum_final<<<dim3(1, 1, 1), 128, 0, stream>>>(csp, csum);
    tcvt<<<dim3(96, 1, 1), 256, 0, stream>>>(fe1, feT1);
    tcvt<<<dim3(96, 1, 1), 256, 0, stream>>>(fe2, feT2);

    // encoder 1: x1 = spike(c0*Asp1@fe1 + c1*Aft1@fe1 + b0*colsum)
    gemm_bf16<true><<<dim3(48, 16, 1), 256, 0, stream>>>(
        Asp1, Asp1, Aft1, c1w, feT1, P, NROWS, NROWS, 384, NROWS, 0);
    reduce_p<<<dim3(1536, 1, 1), 256, 0, stream>>>(P, x1, csum, c1b, 16, 1, 0);
    qkv_kernel<<<96, 256, 0, stream>>>(x1, Wq1, Wk1, Wv1, qb, kb, vb);
    kv_part_kernel<<<96, 256, 0, stream>>>(kb, vb, kvp);
    attn_final<<<96, 256, 0, stream>>>(qb, kvp, Wp1, x1, emb1);

    // encoder 2
    gemm_bf16<true><<<dim3(48, 16, 1), 256, 0, stream>>>(
        Asp2, Asp2, Aft2, c2w, feT2, P, NROWS, NROWS, 384, NROWS, 0);
    reduce_p<<<dim3(1536, 1, 1), 256, 0, stream>>>(P, x2, csum + 64, c2b, 16, 1, 0);
    qkv_kernel<<<96, 256, 0, stream>>>(x2, Wq2, Wk2, Wv2, qb, kb, vb);
    kv_part_kernel<<<96, 256, 0, stream>>>(kb, vb, kvp);
    attn_final<<<96, 256, 0, stream>>>(qb, kvp, Wp2, x2, emb2);

    // MLP combine
    comb_kernel<<<96, 256, 0, stream>>>(emb1, emb2, FC1w, FC1b, FC2w, FC2b, comb, scomb);
    tcvt<<<dim3(96, 1, 1), 256, 0, stream>>>(comb, combT);

    // decoders: g = adj_spatial @ comb, then recon = spike(g @ w_dec)
    gemm_bf16<false><<<dim3(48, 8, 2), 256, 0, stream>>>(
        Asp1, Asp2, nullptr, nullptr, combT, P, NROWS, NROWS, 768, NROWS, PBANK);
    reduce_p<<<dim3(1536, 1, 2), 256, 0, stream>>>(P, g, nullptr, nullptr, 8, 0, PBANK);
    recon_kernel<<<dim3(96, 24, 1), 256, 0, stream>>>(g, Wd1, rec1, DIN1);
    recon_kernel<<<dim3(96, 4, 1), 256, 0, stream>>>(g + NC, Wd2, rec2, DIN2);
}